// Round 10
// baseline (34.462 us; speedup 1.0000x reference)
//
#include <hip/hip_runtime.h>
#include <hip/hip_bf16.h>

// mIoU loss, pair-key histogram, two-stage (no global atomics).
// Ledger:
//  R1: global atomics on 60 addrs -> 313us.
//  R2~R3: DS op mix irrelevant (42us invariant).
//  R4~R6: VGPR-liveness idioms all defeated by allocator (28/36/44 VGPR).
//  R7 ablation: load path indicted (~27us load-only).
//  R8: DMA double-buffer vmcnt(2): 34.6us, 16 waves/CU, 64KB in flight.
//  R9: pair-key 1-atomic/px BUT occupancy halved (67.5KB LDS): 32.7us.
//      -> atomics exonerated as sole wall; residual = latency stalls in
//         a too-shallow (2-deep) DMA pipeline.
//  R10: BOTH levers: NCOPY 32->8 (hist 12.8KB) + 4-deep slot-pairs
//       (vmcnt(6) steady, counted drain 4/2/0). 45KB LDS -> 3 blocks/CU
//       = 12 waves, 8KB in flight/wave = 96KB/CU.

#define NB      20
#define NKEY    (NB * NB)   // 400
#define NCOPY   8
#define BLK     256         // 4 waves
#define NSLOT   4           // slot-pairs in flight
#define GRID_H  768         // exactly 3 blocks/CU
#define PSTRIDE 64          // padded row per block in workspace

// 16B-per-lane DMA: LDS dest = wave-uniform base + lane*16 (m97/m104).
__device__ __forceinline__ void dma16(const void* g, void* l) {
    __builtin_amdgcn_global_load_lds(
        (const __attribute__((address_space(1))) unsigned*)g,
        (__attribute__((address_space(3))) unsigned*)l, 16, 0, 0);
}

__device__ __forceinline__ void process_pix(int p, int t, unsigned* hist_cp) {
    // ONE fire-and-forget LDS atomic per pixel. hist_cp = &s_hist[copy].
    atomicAdd(&hist_cp[(p * NB + t) * NCOPY], 1u);
}

__device__ __forceinline__ void process_vec(int4 pv, int4 tv, unsigned* hist_cp) {
    process_pix(pv.x, tv.x, hist_cp);
    process_pix(pv.y, tv.y, hist_cp);
    process_pix(pv.z, tv.z, hist_cp);
    process_pix(pv.w, tv.w, hist_cp);
}

__global__ __launch_bounds__(BLK) void miou_hist_kernel(
        const int4* __restrict__ preds, const int4* __restrict__ targs,
        unsigned* __restrict__ partials, int n4, int full_iters) {
    __shared__ unsigned s_hist[NKEY * NCOPY];   // 12.8 KB
    __shared__ int4 s_p[NSLOT][BLK];            // 16 KB staging
    __shared__ int4 s_t[NSLOT][BLK];            // 16 KB
    const int tid  = threadIdx.x;
    const int wid  = tid >> 6;
    const int lane = tid & 63;

    for (int k = tid; k < NKEY * NCOPY; k += BLK) s_hist[k] = 0u;
    __syncthreads();

    unsigned* hist_cp = &s_hist[tid & (NCOPY - 1)];
    const int CHUNK = gridDim.x * BLK;
    const int base  = blockIdx.x * BLK + tid;

// One pipeline step: wait for slot J's pair (VM newer ops may remain),
// read it, drain LDS, refill the slot for J+NSLOT, consume.
#define STEP(J, VM) do {                                              \
    const int slot_ = (J) & (NSLOT - 1);                              \
    asm volatile("s_waitcnt vmcnt(" #VM ")" ::: "memory");            \
    int4 pv_ = s_p[slot_][wid * 64 + lane];                           \
    int4 tv_ = s_t[slot_][wid * 64 + lane];                           \
    asm volatile("s_waitcnt lgkmcnt(0)" ::: "memory");                \
    if ((J) + NSLOT < full_iters) {                                   \
        dma16(&preds[base + ((J) + NSLOT) * CHUNK], &s_p[slot_][wid * 64]); \
        dma16(&targs[base + ((J) + NSLOT) * CHUNK], &s_t[slot_][wid * 64]); \
    }                                                                 \
    process_vec(pv_, tv_, hist_cp);                                   \
} while (0)

    if (full_iters >= NSLOT) {   // host guarantees full_iters==0 or >=NSLOT
        #pragma unroll
        for (int s = 0; s < NSLOT; ++s) {
            dma16(&preds[base + s * CHUNK], &s_p[s][wid * 64]);
            dma16(&targs[base + s * CHUNK], &s_t[s][wid * 64]);
        }
        int j = 0;
        for (; j < full_iters - (NSLOT - 1); ++j) STEP(j, 6);
        STEP(j, 4); ++j;    // counted drain: 2 pairs left in flight
        STEP(j, 2); ++j;    // 1 pair left
        STEP(j, 0);         // drained
    }
    // Tail (plain loads; covers the 0.33-chunk remainder and tiny shapes).
    for (int i = base + full_iters * CHUNK; i < n4; i += CHUNK) {
        int4 pv = preds[i];
        int4 tv = targs[i];
        process_vec(pv, tv, hist_cp);
    }
#undef STEP
    __syncthreads();

    // Marginals: wave w handles classes w, w+4, ..., <NB.
    //  pc[c] = 160 contiguous words at c*160 (all t, all copies)
    //  tc[c] = for p in 0..19: 8 words at (p*20+c)*8
    //  ic[c] = 8 words at c*168
    unsigned* dst = &partials[(size_t)blockIdx.x * PSTRIDE];
    for (int c = wid; c < NB; c += (BLK / 64)) {
        unsigned pcs = 0;
        pcs += s_hist[c * 160 + lane];
        pcs += s_hist[c * 160 + 64 + lane];
        if (lane < 32) pcs += s_hist[c * 160 + 128 + lane];

        unsigned tcs = 0;
        {
            const int p  = lane >> 3;    // 0..7
            const int cp = lane & 7;
            tcs += s_hist[(p * NB + c) * NCOPY + cp];
            tcs += s_hist[((p + 8) * NB + c) * NCOPY + cp];
            if (p < 4) tcs += s_hist[((p + 16) * NB + c) * NCOPY + cp];
        }
        unsigned ics = (lane < NCOPY) ? s_hist[c * 21 * NCOPY + lane] : 0u;

        #pragma unroll
        for (int off = 32; off > 0; off >>= 1) {
            pcs += __shfl_xor(pcs, off);
            tcs += __shfl_xor(tcs, off);
            ics += __shfl_xor(ics, off);
        }
        if (lane == 0) {
            dst[c]          = pcs;
            dst[NB + c]     = tcs;
            dst[2 * NB + c] = ics;
        }
    }
}

// One block, 1024 threads. partials = nblocks rows x 16 int4 (coalesced).
__global__ __launch_bounds__(1024) void miou_reduce_kernel(
        const unsigned* __restrict__ partials, int nblocks,
        const int* __restrict__ nb_ptr, const int* __restrict__ smooth_ptr,
        float* __restrict__ out) {
    __shared__ unsigned s_tot[PSTRIDE];
    if (threadIdx.x < PSTRIDE) s_tot[threadIdx.x] = 0u;
    __syncthreads();

    const int col4 = threadIdx.x & 15;
    const int seg  = threadIdx.x >> 4;
    const int4* p4 = (const int4*)partials;

    unsigned ax = 0, ay = 0, az = 0, aw = 0;
    #pragma unroll 8
    for (int r = seg; r < nblocks; r += 64) {
        int4 v = p4[r * 16 + col4];
        ax += (unsigned)v.x; ay += (unsigned)v.y;
        az += (unsigned)v.z; aw += (unsigned)v.w;
    }
    atomicAdd(&s_tot[col4 * 4 + 0], ax);
    atomicAdd(&s_tot[col4 * 4 + 1], ay);
    atomicAdd(&s_tot[col4 * 4 + 2], az);
    atomicAdd(&s_tot[col4 * 4 + 3], aw);
    __syncthreads();

    if (threadIdx.x == 0) {
        const int   nb = *nb_ptr;
        const float s  = (float)(*smooth_ptr);
        float acc_iou = 0.0f;
        for (int c = 0; c < nb && c < NB; ++c) {
            float pc    = (float)s_tot[c];
            float tc    = (float)s_tot[NB + c];
            float inter = (float)s_tot[2 * NB + c];
            float uni   = pc + tc - inter;
            acc_iou += (inter + s) / (uni + s);
        }
        out[0] = 1.0f - acc_iou / (float)nb;
    }
}

extern "C" void kernel_launch(void* const* d_in, const int* in_sizes, int n_in,
                              void* d_out, int out_size, void* d_ws, size_t ws_size,
                              hipStream_t stream) {
    const int4* preds      = (const int4*)d_in[0];
    const int4* targs      = (const int4*)d_in[1];
    const int*  nb_ptr     = (const int*)d_in[2];
    const int*  smooth_ptr = (const int*)d_in[3];
    float*      out        = (float*)d_out;

    int n  = in_sizes[0];
    int n4 = n >> 2;  // 16M pixels, divisible by 4

    unsigned* partials = (unsigned*)d_ws;

    int grid = GRID_H;
    int max_grid = (n4 + BLK - 1) / BLK;
    if (grid > max_grid) grid = max_grid;
    size_t need_per_block = PSTRIDE * sizeof(unsigned);
    if ((size_t)grid * need_per_block > ws_size)
        grid = (int)(ws_size / need_per_block);

    int chunk = grid * BLK;
    int full  = (chunk > 0) ? (n4 / chunk) : 0;
    if (full < NSLOT) full = 0;   // tiny shapes -> tail path handles all

    miou_hist_kernel<<<grid, BLK, 0, stream>>>(preds, targs, partials, n4, full);
    miou_reduce_kernel<<<1, 1024, 0, stream>>>(partials, grid, nb_ptr, smooth_ptr, out);
}